// Round 2
// 1568.631 us; speedup vs baseline: 1.0484x; 1.0484x over previous
//
#include <hip/hip_runtime.h>
#include <hip/hip_bf16.h>
#include <math.h>

#define TT 64
#define BB 32
#define HID 256
#define NA 12
#define FEAT 1152
#define NB 2048           // T*B
#define G3 768            // 3*HID

typedef __hip_bfloat16 bf16;
typedef __attribute__((ext_vector_type(8))) short short8;
typedef __attribute__((ext_vector_type(4))) float f32x4;
typedef __attribute__((ext_vector_type(4))) unsigned int u32x4;

static __device__ __forceinline__ float bf2f(bf16 v) { return __bfloat162float(v); }
static __device__ __forceinline__ bf16 f2bf(float v) { return __float2bfloat16(v); }

#define MFMA(a, b, c) __builtin_amdgcn_mfma_f32_16x16x32_bf16((a), (b), (c), 0, 0, 0)

// ============================================================================
// prep: build fragment-ordered bf16 weights once.
//   A: lane l holds A[m=l&15][k=8*(l>>4)+j]
//   B: lane l holds B[k=8*(l>>4)+j][n=l&15]
//   D: lane l reg r holds D[row=4*(l>>4)+r][col=l&15]
// whh16: straight bf16 copy of W_hh [768][256] row-major (for VGPR-resident scan)
// ============================================================================
__global__ __launch_bounds__(256) void prep_kernel(
    const float* __restrict__ w1, const float* __restrict__ w2,
    const float* __restrict__ w3, const float* __restrict__ w4,
    const float* __restrict__ W_ih, const float* __restrict__ W_hh,
    const float* __restrict__ b_ih, const float* __restrict__ b_hh,
    bf16* __restrict__ wB1, bf16* __restrict__ wB2,
    bf16* __restrict__ wB3, bf16* __restrict__ wB4,
    bf16* __restrict__ wihF, bf16* __restrict__ whh16, float* __restrict__ biasg)
{
    int i = blockIdx.x * 256 + threadIdx.x;
    if (i < 2048) {              // wB1[nt][ch][lane][j], K=36 padded to 64
        int j = i & 7, l = (i >> 3) & 63, rest = i >> 9;
        int ch = rest & 1, nt = rest >> 1;
        int k = ch * 32 + 8 * (l >> 4) + j;          // k = kk*4 + ci
        int co = nt * 16 + (l & 15);
        wB1[i] = f2bf(k < 36 ? w1[co * 36 + (k & 3) * 9 + (k >> 2)] : 0.0f);
    }
    if (i < 9216) {              // wB2/3/4[nt][kk][lane][j], k = kk*32 + ci
        int j = i & 7, l = (i >> 3) & 63, rest = i >> 9;
        int kk = rest % 9, nt = rest / 9;
        int ci = 8 * (l >> 4) + j, co = nt * 16 + (l & 15);
        wB2[i] = f2bf(w2[co * 288 + ci * 9 + kk]);
        wB3[i] = f2bf(w3[co * 288 + ci * 9 + kk]);
        wB4[i] = f2bf(w4[co * 288 + ci * 9 + kk]);
    }
    if (i < 884736) {            // wihF[ch(36)][st(48)][lane][j]
        int j = i & 7, l = (i >> 3) & 63, rest = i >> 9;
        int st = rest % 48, ch = rest / 48;
        int k = ch * 32 + 8 * (l >> 4) + j, n = st * 16 + (l & 15);
        wihF[i] = f2bf(W_ih[(size_t)n * FEAT + k]);
    }
    if (i < 196608) {            // whh16 flat bf16 copy, [g][k] row-major
        whh16[i] = f2bf(W_hh[i]);
    }
    if (i < G3) biasg[i] = b_ih[i] + (i < 2 * HID ? b_hh[i] : 0.0f);
}

// ============================================================================
// conv1: [CH,4,84,84] f32 -> x1 [CH,42,42,32] bf16 channel-last. K=36 pad 64.
// ============================================================================
__global__ __launch_bounds__(256) void conv1_kernel(
    const float* __restrict__ in, int n0,
    const bf16* __restrict__ wB1g, const float* __restrict__ b1,
    bf16* __restrict__ x1)
{
    __shared__ bf16 ins[7 * 84 * 4];   // [r][x][ci]
    __shared__ bf16 A[64 * 72];        // KP1 = 72 (64 + 8 pad)
    __shared__ bf16 wBs[2048];
    int tid = threadIdx.x;
    int nl = blockIdx.x / 28, blk = blockIdx.x % 28;
    int n = n0 + nl;
    int p0 = blk * 64;
    int oy_lo = p0 / 42;
    int oy_hi = (p0 + 63) / 42; if (oy_hi > 41) oy_hi = 41;
    int y_lo = 2 * oy_lo - 1;
    int rows = 2 * oy_hi + 2 - y_lo;   // <= 7

    if (tid < 256) ((uint4*)wBs)[tid] = ((const uint4*)wB1g)[tid];
    const float* inb = in + (size_t)n * 4 * 7056;
    for (int i = tid; i < rows * 336; i += 256) {
        int r = i / 336, rem = i % 336, ci = rem / 84, x = rem % 84;
        int y = y_lo + r;
        float v = (y >= 0) ? inb[ci * 7056 + y * 84 + x] : 0.0f;
        ins[(r * 84 + x) * 4 + ci] = f2bf(v);
    }
    __syncthreads();
    for (int i = tid; i < 576; i += 256) {
        int m = i / 9, q = i % 9;
        uint2 z; z.x = 0u; z.y = 0u;
        *(uint2*)&A[m * 72 + 36 + q * 4] = z;
    }
    for (int i = tid; i < 576; i += 256) {
        int m = i / 9, kk = i % 9;
        int kh = kk / 3, kw = kk - kh * 3;
        int p = p0 + m;
        uint2 v; v.x = 0u; v.y = 0u;
        if (p < 1764) {
            int oy = p / 42, ox = p - oy * 42;
            int y = 2 * oy - 1 + kh, x = 2 * ox - 1 + kw;
            if ((unsigned)y < 84u && (unsigned)x < 84u)
                v = *(const uint2*)&ins[((y - y_lo) * 84 + x) * 4];
        }
        *(uint2*)&A[m * 72 + kk * 4] = v;
    }
    __syncthreads();
    int lane = tid & 63, g = tid >> 6, quad = lane >> 4, c16 = lane & 15;
    int ma = g * 16 + c16;
    short8 a0 = *(const short8*)&A[ma * 72 + quad * 8];
    short8 a1 = *(const short8*)&A[ma * 72 + 32 + quad * 8];
    #pragma unroll
    for (int nt = 0; nt < 2; nt++) {
        float bv = b1[nt * 16 + c16];
        f32x4 acc = {bv, bv, bv, bv};
        short8 b0 = *(const short8*)&wBs[((nt * 2 + 0) * 64 + lane) * 8];
        short8 bq = *(const short8*)&wBs[((nt * 2 + 1) * 64 + lane) * 8];
        acc = MFMA(a0, b0, acc);
        acc = MFMA(a1, bq, acc);
        #pragma unroll
        for (int r = 0; r < 4; r++) {
            int p = p0 + g * 16 + 4 * quad + r;
            if (p < 1764) {
                float v = acc[r];
                v = v > 0.0f ? v : expm1f(v);
                x1[((size_t)nl * 1764 + p) * 32 + nt * 16 + c16] = f2bf(v);
            }
        }
    }
}

// ============================================================================
// convN (conv2/3/4): channel-last bf16 in, 3x3 s2 p1, Cin=Cout=32, K=288.
// ============================================================================
template<int HI, int HO, int OUTMODE>
__global__ __launch_bounds__(256) void convN_kernel(
    const bf16* __restrict__ xin, bf16* __restrict__ xout,
    const bf16* __restrict__ wBg, const float* __restrict__ bias, int n0)
{
    constexpr int NPIX = HO * HO;
    constexpr int NBLK = (NPIX + 63) / 64;
    __shared__ bf16 A[64 * 296];       // 37,888 B
    __shared__ bf16 wBs[9216];         // 18,432 B
    int tid = threadIdx.x;
    int nl = blockIdx.x / NBLK, blk = blockIdx.x % NBLK;
    int p0 = blk * 64;
    for (int i = tid; i < 1152; i += 256) ((uint4*)wBs)[i] = ((const uint4*)wBg)[i];
    const bf16* xb = xin + (size_t)nl * HI * HI * 32;
    for (int i = tid; i < 2304; i += 256) {
        int m = i / 36, t = i % 36, kk = t >> 2, part = t & 3;
        int kh = kk / 3, kw = kk - kh * 3;
        int p = p0 + m;
        uint4 v; v.x = v.y = v.z = v.w = 0u;
        if (p < NPIX) {
            int oy = p / HO, ox = p - oy * HO;
            int y = 2 * oy - 1 + kh, x = 2 * ox - 1 + kw;
            if ((unsigned)y < (unsigned)HI && (unsigned)x < (unsigned)HI)
                v = *(const uint4*)&xb[((size_t)(y * HI + x)) * 32 + part * 8];
        }
        *(uint4*)&A[m * 296 + kk * 32 + part * 8] = v;
    }
    __syncthreads();
    int lane = tid & 63, g = tid >> 6, quad = lane >> 4, c16 = lane & 15;
    int ma = g * 16 + c16;
    short8 af[9];
    #pragma unroll
    for (int kk = 0; kk < 9; kk++)
        af[kk] = *(const short8*)&A[ma * 296 + kk * 32 + quad * 8];
    #pragma unroll
    for (int nt = 0; nt < 2; nt++) {
        float bv = bias[nt * 16 + c16];
        f32x4 acc = {bv, bv, bv, bv};
        #pragma unroll
        for (int kk = 0; kk < 9; kk++) {
            short8 bfr = *(const short8*)&wBs[((nt * 9 + kk) * 64 + lane) * 8];
            acc = MFMA(af[kk], bfr, acc);
        }
        #pragma unroll
        for (int r = 0; r < 4; r++) {
            int p = p0 + g * 16 + 4 * quad + r;
            if (p < NPIX) {
                float v = acc[r];
                v = v > 0.0f ? v : expm1f(v);
                if (OUTMODE == 0)
                    xout[(((size_t)(n0 + nl)) * NPIX + p) * 32 + nt * 16 + c16] = f2bf(v);
                else
                    xout[(size_t)(n0 + nl) * FEAT + (nt * 16 + c16) * 36 + p] = f2bf(v);
            }
        }
    }
}

// ============================================================================
// GI = x4 @ W_ih^T + biasg : [2048,1152]bf16 x [1152,768] -> f32. MFMA.
// ============================================================================
__global__ __launch_bounds__(256) void gemm_gi_kernel(
    const bf16* __restrict__ X, const bf16* __restrict__ wihF,
    const float* __restrict__ biasg, float* __restrict__ GI)
{
    __shared__ bf16 As[64 * 40];
    int tid = threadIdx.x;
    int m0 = blockIdx.x * 64, nb = blockIdx.y * 4, n0 = blockIdx.y * 64;
    int lane = tid & 63, g = tid >> 6, quad = lane >> 4, c16 = lane & 15;
    f32x4 acc[4];
    #pragma unroll
    for (int st = 0; st < 4; st++) {
        float bv = biasg[n0 + st * 16 + c16];
        acc[st] = (f32x4){bv, bv, bv, bv};
    }
    int sm = tid >> 2, sp = tid & 3;
    for (int ch = 0; ch < 36; ch++) {
        __syncthreads();
        *(uint4*)&As[sm * 40 + sp * 8] =
            *(const uint4*)&X[(size_t)(m0 + sm) * FEAT + ch * 32 + sp * 8];
        __syncthreads();
        short8 af = *(const short8*)&As[(g * 16 + c16) * 40 + quad * 8];
        #pragma unroll
        for (int st = 0; st < 4; st++) {
            short8 bfr = *(const short8*)&wihF[(((size_t)ch * 48 + nb + st) * 64 + lane) * 8];
            acc[st] = MFMA(af, bfr, acc[st]);
        }
    }
    #pragma unroll
    for (int st = 0; st < 4; st++)
        #pragma unroll
        for (int r = 0; r < 4; r++)
            GI[(size_t)(m0 + g * 16 + 4 * quad + r) * G3 + n0 + st * 16 + c16] = acc[st][r];
}

// ============================================================================
// GRU scan: 32 blocks x 768 threads (one per gate-column).
//
// Round-N fix: the named-scalar uint4[32] scheme spilled (VGPR_Count=84,
// 24.5K cy/step). New scheme: 24 uint4 (96 VGPR, k=0..191) pinned via opaque
// asm (defs become asm results: non-rematerializable; 96+~40 working regs
// leaves slack under the 768-thread cap of ~168 so nothing spills).
// Remaining 8 uint4 (k=192..255) are deliberately re-loaded from L2 each
// step through a per-iteration opaqued pointer (blocks LICM), issued at loop
// top and consumed ~3000 cy later -> latency hidden. Dot uses 4 independent
// acc chains (dep distance > FMA latency -> one wave saturates issue).
// ============================================================================
#define UNPK_LO(u) __uint_as_float((u) << 16)
#define UNPK_HI(u) __uint_as_float((u) & 0xffff0000u)
#define WDOT8(Wv, hbase, A_) {                                                 \
    float4 h0 = *(const float4*)&hs[(hbase)];                                  \
    float4 h1 = *(const float4*)&hs[(hbase) + 4];                              \
    A_ = fmaf(h0.x, UNPK_LO((Wv).x), A_);                                      \
    A_ = fmaf(h0.y, UNPK_HI((Wv).x), A_);                                      \
    A_ = fmaf(h0.z, UNPK_LO((Wv).y), A_);                                      \
    A_ = fmaf(h0.w, UNPK_HI((Wv).y), A_);                                      \
    A_ = fmaf(h1.x, UNPK_LO((Wv).z), A_);                                      \
    A_ = fmaf(h1.y, UNPK_HI((Wv).z), A_);                                      \
    A_ = fmaf(h1.z, UNPK_LO((Wv).w), A_);                                      \
    A_ = fmaf(h1.w, UNPK_HI((Wv).w), A_); }

__global__ __launch_bounds__(768, 3) void scan_kernel(
    const float* __restrict__ GI, const bf16* __restrict__ whh16,
    const float* __restrict__ b_hh, const float* __restrict__ rnn_in,
    const float* __restrict__ mask, float* __restrict__ H)
{
    __shared__ float hs[HID];
    __shared__ float pr[HID];
    __shared__ float pz[HID];
    __shared__ float pn[HID];
    int b = blockIdx.x, t = threadIdx.x;
    int gate = t >> 8, j = t & 255;

    const u32x4* wr = (const u32x4*)(whh16 + (size_t)t * HID);
    // k = 0..191 : pinned in VGPRs (96 regs).
    u32x4 w0  = wr[0],  w1  = wr[1],  w2  = wr[2],  w3  = wr[3];
    u32x4 w4  = wr[4],  w5  = wr[5],  w6  = wr[6],  w7  = wr[7];
    u32x4 w8  = wr[8],  w9  = wr[9],  w10 = wr[10], w11 = wr[11];
    u32x4 w12 = wr[12], w13 = wr[13], w14 = wr[14], w15 = wr[15];
    u32x4 w16 = wr[16], w17 = wr[17], w18 = wr[18], w19 = wr[19];
    u32x4 w20 = wr[20], w21 = wr[21], w22 = wr[22], w23 = wr[23];
    asm volatile("" : "+v"(w0), "+v"(w1), "+v"(w2), "+v"(w3),
                      "+v"(w4), "+v"(w5), "+v"(w6), "+v"(w7));
    asm volatile("" : "+v"(w8), "+v"(w9), "+v"(w10), "+v"(w11),
                      "+v"(w12), "+v"(w13), "+v"(w14), "+v"(w15));
    asm volatile("" : "+v"(w16), "+v"(w17), "+v"(w18), "+v"(w19),
                      "+v"(w20), "+v"(w21), "+v"(w22), "+v"(w23));

    float bhn = (gate == 2) ? b_hh[2 * HID + j] : 0.0f;
    if (t < HID) hs[t] = rnn_in[b * HID + t] * mask[b];
    __syncthreads();

    #pragma unroll 1
    for (int step = 0; step < TT; step++) {
        int row = step * BB + b;
        // combiner-thread prefetches (issued before the dot, consumed after barrier)
        float gr = 0.f, gz = 0.f, gn = 0.f, hold = 0.f, mnext = 1.0f;
        if (gate == 0) {
            const float* gp = GI + (size_t)row * G3 + j;
            gr = gp[0]; gz = gp[256]; gn = gp[512];
            hold = hs[j];
            if (step + 1 < TT) mnext = mask[(step + 1) * BB + b];
        }
        // k = 192..255 : streamed from L2 each step. Opaque the pointer per
        // iteration so LICM can't hoist these into long (spilling) live ranges.
        uintptr_t wpo = (uintptr_t)wr;
        asm volatile("" : "+v"(wpo));
        const u32x4* wt = (const u32x4*)wpo;
        u32x4 t24 = wt[24], t25 = wt[25], t26 = wt[26], t27 = wt[27];
        u32x4 t28 = wt[28], t29 = wt[29], t30 = wt[30], t31 = wt[31];

        float a0 = bhn, a1 = 0.f, a2 = 0.f, a3 = 0.f;
        WDOT8(w0,    0, a0)  WDOT8(w1,    8, a1)  WDOT8(w2,   16, a2)  WDOT8(w3,   24, a3)
        WDOT8(w4,   32, a0)  WDOT8(w5,   40, a1)  WDOT8(w6,   48, a2)  WDOT8(w7,   56, a3)
        WDOT8(w8,   64, a0)  WDOT8(w9,   72, a1)  WDOT8(w10,  80, a2)  WDOT8(w11,  88, a3)
        WDOT8(w12,  96, a0)  WDOT8(w13, 104, a1)  WDOT8(w14, 112, a2)  WDOT8(w15, 120, a3)
        WDOT8(w16, 128, a0)  WDOT8(w17, 136, a1)  WDOT8(w18, 144, a2)  WDOT8(w19, 152, a3)
        WDOT8(w20, 160, a0)  WDOT8(w21, 168, a1)  WDOT8(w22, 176, a2)  WDOT8(w23, 184, a3)
        WDOT8(t24, 192, a0)  WDOT8(t25, 200, a1)  WDOT8(t26, 208, a2)  WDOT8(t27, 216, a3)
        WDOT8(t28, 224, a0)  WDOT8(t29, 232, a1)  WDOT8(t30, 240, a2)  WDOT8(t31, 248, a3)
        float acc = (a0 + a1) + (a2 + a3);

        if (gate == 0)      pr[j] = acc;
        else if (gate == 1) pz[j] = acc;
        else                pn[j] = acc;
        __syncthreads();
        if (gate == 0) {
            float r = 1.0f / (1.0f + expf(-(gr + pr[j])));
            float z = 1.0f / (1.0f + expf(-(gz + pz[j])));
            float pre = gn + r * pn[j];
            pre = fminf(15.0f, fmaxf(-15.0f, pre));
            float e = expf(2.0f * pre);
            float nn = (e - 1.0f) / (e + 1.0f);
            float hnew = (1.0f - z) * nn + z * hold;
            H[(size_t)row * HID + j] = hnew;
            hs[j] = hnew * mnext;
        }
        __syncthreads();
    }
}

// ---------------- heads: v, actions, logp_a, ent (float32 out) ----------------
__global__ __launch_bounds__(256) void heads_kernel(
    const float* __restrict__ H, const int* __restrict__ actions,
    const float* __restrict__ Wc, const float* __restrict__ bc,
    const float* __restrict__ Wa, const float* __restrict__ ba,
    float* __restrict__ out)
{
    int r = blockIdx.x * 256 + threadIdx.x;
    if (r >= NB) return;
    const float* h = H + (size_t)r * HID;
    float v = bc[0];
    for (int k = 0; k < HID; k++) v += h[k] * Wc[k];
    float lg[NA];
    for (int a = 0; a < NA; a++) {
        float s = ba[a];
        const float* wa = Wa + a * HID;
        for (int k = 0; k < HID; k++) s += h[k] * wa[k];
        lg[a] = s;
    }
    float mx = lg[0];
    for (int a = 1; a < NA; a++) mx = fmaxf(mx, lg[a]);
    float Z = 0.f;
    for (int a = 0; a < NA; a++) Z += expf(lg[a] - mx);
    float lse = mx + logf(Z);
    int act = actions[r];
    float logp_a = lg[act] - lse;
    float ent = 0.f;
    for (int a = 0; a < NA; a++) {
        float lp = lg[a] - lse;
        ent -= expf(lp) * lp;
    }
    out[r]          = v;
    out[NB + r]     = (float)act;
    out[2 * NB + r] = logp_a;
    out[3 * NB + r] = ent;
}

__global__ __launch_bounds__(256) void hfin_kernel(const float* __restrict__ H, float* __restrict__ out)
{
    int i = blockIdx.x * 256 + threadIdx.x;
    if (i < BB * HID)
        out[4 * NB + i] = H[(size_t)(TT - 1) * BB * HID + i];
}

extern "C" void kernel_launch(void* const* d_in, const int* in_sizes, int n_in,
                              void* d_out, int out_size, void* d_ws, size_t ws_size,
                              hipStream_t stream) {
    const float* inputs  = (const float*)d_in[0];
    const float* rnn_in  = (const float*)d_in[1];
    const float* mask    = (const float*)d_in[2];
    const int*   actions = (const int*)d_in[3];
    const float* w1 = (const float*)d_in[4];
    const float* b1 = (const float*)d_in[5];
    const float* w2 = (const float*)d_in[6];
    const float* b2 = (const float*)d_in[7];
    const float* w3 = (const float*)d_in[8];
    const float* b3 = (const float*)d_in[9];
    const float* w4 = (const float*)d_in[10];
    const float* b4 = (const float*)d_in[11];
    const float* W_ih = (const float*)d_in[12];
    const float* W_hh = (const float*)d_in[13];
    const float* b_ih = (const float*)d_in[14];
    const float* b_hh = (const float*)d_in[15];
    const float* Wc = (const float*)d_in[16];
    const float* bc = (const float*)d_in[17];
    const float* Wa = (const float*)d_in[18];
    const float* ba = (const float*)d_in[19];
    float* out = (float*)d_out;

    char* ws = (char*)d_ws;
    size_t o = 0;
    auto nxt = [&](size_t b) { void* p = ws + o; o += (b + 255) & ~(size_t)255; return p; };
    bf16* wB1  = (bf16*)nxt(2048 * 2);
    bf16* wB2  = (bf16*)nxt(9216 * 2);
    bf16* wB3  = (bf16*)nxt(9216 * 2);
    bf16* wB4  = (bf16*)nxt(9216 * 2);
    bf16* wihF = (bf16*)nxt(884736 * 2);
    bf16* whh16 = (bf16*)nxt(196608 * 2);
    float* biasg = (float*)nxt(768 * 4);
    bf16* x4 = (bf16*)nxt((size_t)NB * FEAT * 2);            //  4.72 MB
    bf16* x2 = (bf16*)nxt((size_t)NB * 441 * 32 * 2);        // 57.80 MB

    // dynamic conv1/conv2 chunking based on available workspace
    const size_t X1_PER_IMG = 1764 * 32 * 2;                  // 112,896 B
    const size_t TAILFIX = 15859712 + 6291456 + 2097152 + 1024; // x3+GI+H
    bf16* x3; float* GI; float* H; bf16* x1c;
    int CH;
    if (ws_size >= o + TAILFIX + 2048 * X1_PER_IMG + (1u << 20)) {
        CH = 2048;
        x3 = (bf16*)nxt(15859712); GI = (float*)nxt(6291456); H = (float*)nxt(2097152);
        x1c = (bf16*)nxt(2048 * X1_PER_IMG);
    } else if (ws_size >= o + TAILFIX + 512 * X1_PER_IMG + (1u << 20)) {
        CH = 512;
        x3 = (bf16*)nxt(15859712); GI = (float*)nxt(6291456); H = (float*)nxt(2097152);
        x1c = (bf16*)nxt(512 * X1_PER_IMG);
    } else if (ws_size >= o + TAILFIX + 256 * X1_PER_IMG + (1u << 20)) {
        CH = 256;
        x3 = (bf16*)nxt(15859712); GI = (float*)nxt(6291456); H = (float*)nxt(2097152);
        x1c = (bf16*)nxt(256 * X1_PER_IMG);
    } else {
        // known-good overlay layout (93.7 MB total): x1c shares region with x3/GI/H
        CH = 256;
        char* R1 = (char*)nxt(28901376);
        x1c = (bf16*)R1;
        x3  = (bf16*)R1;
        GI  = (float*)(R1 + 15859712);
        H   = (float*)(R1 + 15859712 + 6291456);
    }

    prep_kernel<<<3456, 256, 0, stream>>>(w1, w2, w3, w4, W_ih, W_hh, b_ih, b_hh,
                                          wB1, wB2, wB3, wB4, wihF, whh16, biasg);
    for (int c = 0; c < 2048 / CH; c++) {
        conv1_kernel<<<CH * 28, 256, 0, stream>>>(inputs, c * CH, wB1, b1, x1c);
        convN_kernel<42, 21, 0><<<CH * 7, 256, 0, stream>>>(x1c, x2, wB2, b2, c * CH);
    }
    convN_kernel<21, 11, 0><<<2048 * 2, 256, 0, stream>>>(x2, x3, wB3, b3, 0);
    convN_kernel<11, 6, 1><<<2048, 256, 0, stream>>>(x3, x4, wB4, b4, 0);
    gemm_gi_kernel<<<dim3(32, 12), 256, 0, stream>>>(x4, wihF, biasg, GI);
    scan_kernel<<<BB, 768, 0, stream>>>(GI, whh16, b_hh, rnn_in, mask, H);
    heads_kernel<<<NB / 256, 256, 0, stream>>>(H, actions, Wc, bc, Wa, ba, out);
    hfin_kernel<<<(BB * HID + 255) / 256, 256, 0, stream>>>(H, out);
}

// Round 3
// 1568.437 us; speedup vs baseline: 1.0485x; 1.0001x over previous
//
#include <hip/hip_runtime.h>
#include <hip/hip_bf16.h>
#include <math.h>

#define TT 64
#define BB 32
#define HID 256
#define NA 12
#define FEAT 1152
#define NB 2048           // T*B
#define G3 768            // 3*HID

typedef __hip_bfloat16 bf16;
typedef __attribute__((ext_vector_type(8))) short short8;
typedef __attribute__((ext_vector_type(4))) float f32x4;
typedef __attribute__((ext_vector_type(4))) unsigned int u32x4;

static __device__ __forceinline__ float bf2f(bf16 v) { return __bfloat162float(v); }
static __device__ __forceinline__ bf16 f2bf(float v) { return __float2bfloat16(v); }

#define MFMA(a, b, c) __builtin_amdgcn_mfma_f32_16x16x32_bf16((a), (b), (c), 0, 0, 0)

// ============================================================================
// prep: build fragment-ordered bf16 weights once.
//   A: lane l holds A[m=l&15][k=8*(l>>4)+j]
//   B: lane l holds B[k=8*(l>>4)+j][n=l&15]
//   D: lane l reg r holds D[row=4*(l>>4)+r][col=l&15]
// whh16: straight bf16 copy of W_hh [768][256] row-major (for VGPR-resident scan)
// ============================================================================
__global__ __launch_bounds__(256) void prep_kernel(
    const float* __restrict__ w1, const float* __restrict__ w2,
    const float* __restrict__ w3, const float* __restrict__ w4,
    const float* __restrict__ W_ih, const float* __restrict__ W_hh,
    const float* __restrict__ b_ih, const float* __restrict__ b_hh,
    bf16* __restrict__ wB1, bf16* __restrict__ wB2,
    bf16* __restrict__ wB3, bf16* __restrict__ wB4,
    bf16* __restrict__ wihF, bf16* __restrict__ whh16, float* __restrict__ biasg)
{
    int i = blockIdx.x * 256 + threadIdx.x;
    if (i < 2048) {              // wB1[nt][ch][lane][j], K=36 padded to 64
        int j = i & 7, l = (i >> 3) & 63, rest = i >> 9;
        int ch = rest & 1, nt = rest >> 1;
        int k = ch * 32 + 8 * (l >> 4) + j;          // k = kk*4 + ci
        int co = nt * 16 + (l & 15);
        wB1[i] = f2bf(k < 36 ? w1[co * 36 + (k & 3) * 9 + (k >> 2)] : 0.0f);
    }
    if (i < 9216) {              // wB2/3/4[nt][kk][lane][j], k = kk*32 + ci
        int j = i & 7, l = (i >> 3) & 63, rest = i >> 9;
        int kk = rest % 9, nt = rest / 9;
        int ci = 8 * (l >> 4) + j, co = nt * 16 + (l & 15);
        wB2[i] = f2bf(w2[co * 288 + ci * 9 + kk]);
        wB3[i] = f2bf(w3[co * 288 + ci * 9 + kk]);
        wB4[i] = f2bf(w4[co * 288 + ci * 9 + kk]);
    }
    if (i < 884736) {            // wihF[ch(36)][st(48)][lane][j]
        int j = i & 7, l = (i >> 3) & 63, rest = i >> 9;
        int st = rest % 48, ch = rest / 48;
        int k = ch * 32 + 8 * (l >> 4) + j, n = st * 16 + (l & 15);
        wihF[i] = f2bf(W_ih[(size_t)n * FEAT + k]);
    }
    if (i < 196608) {            // whh16 flat bf16 copy, [g][k] row-major
        whh16[i] = f2bf(W_hh[i]);
    }
    if (i < G3) biasg[i] = b_ih[i] + (i < 2 * HID ? b_hh[i] : 0.0f);
}

// ============================================================================
// conv1: [CH,4,84,84] f32 -> x1 [CH,42,42,32] bf16 channel-last. K=36 pad 64.
// ============================================================================
__global__ __launch_bounds__(256) void conv1_kernel(
    const float* __restrict__ in, int n0,
    const bf16* __restrict__ wB1g, const float* __restrict__ b1,
    bf16* __restrict__ x1)
{
    __shared__ bf16 ins[7 * 84 * 4];   // [r][x][ci]
    __shared__ bf16 A[64 * 72];        // KP1 = 72 (64 + 8 pad)
    __shared__ bf16 wBs[2048];
    int tid = threadIdx.x;
    int nl = blockIdx.x / 28, blk = blockIdx.x % 28;
    int n = n0 + nl;
    int p0 = blk * 64;
    int oy_lo = p0 / 42;
    int oy_hi = (p0 + 63) / 42; if (oy_hi > 41) oy_hi = 41;
    int y_lo = 2 * oy_lo - 1;
    int rows = 2 * oy_hi + 2 - y_lo;   // <= 7

    if (tid < 256) ((uint4*)wBs)[tid] = ((const uint4*)wB1g)[tid];
    const float* inb = in + (size_t)n * 4 * 7056;
    for (int i = tid; i < rows * 336; i += 256) {
        int r = i / 336, rem = i % 336, ci = rem / 84, x = rem % 84;
        int y = y_lo + r;
        float v = (y >= 0) ? inb[ci * 7056 + y * 84 + x] : 0.0f;
        ins[(r * 84 + x) * 4 + ci] = f2bf(v);
    }
    __syncthreads();
    for (int i = tid; i < 576; i += 256) {
        int m = i / 9, q = i % 9;
        uint2 z; z.x = 0u; z.y = 0u;
        *(uint2*)&A[m * 72 + 36 + q * 4] = z;
    }
    for (int i = tid; i < 576; i += 256) {
        int m = i / 9, kk = i % 9;
        int kh = kk / 3, kw = kk - kh * 3;
        int p = p0 + m;
        uint2 v; v.x = 0u; v.y = 0u;
        if (p < 1764) {
            int oy = p / 42, ox = p - oy * 42;
            int y = 2 * oy - 1 + kh, x = 2 * ox - 1 + kw;
            if ((unsigned)y < 84u && (unsigned)x < 84u)
                v = *(const uint2*)&ins[((y - y_lo) * 84 + x) * 4];
        }
        *(uint2*)&A[m * 72 + kk * 4] = v;
    }
    __syncthreads();
    int lane = tid & 63, g = tid >> 6, quad = lane >> 4, c16 = lane & 15;
    int ma = g * 16 + c16;
    short8 a0 = *(const short8*)&A[ma * 72 + quad * 8];
    short8 a1 = *(const short8*)&A[ma * 72 + 32 + quad * 8];
    #pragma unroll
    for (int nt = 0; nt < 2; nt++) {
        float bv = b1[nt * 16 + c16];
        f32x4 acc = {bv, bv, bv, bv};
        short8 b0 = *(const short8*)&wBs[((nt * 2 + 0) * 64 + lane) * 8];
        short8 bq = *(const short8*)&wBs[((nt * 2 + 1) * 64 + lane) * 8];
        acc = MFMA(a0, b0, acc);
        acc = MFMA(a1, bq, acc);
        #pragma unroll
        for (int r = 0; r < 4; r++) {
            int p = p0 + g * 16 + 4 * quad + r;
            if (p < 1764) {
                float v = acc[r];
                v = v > 0.0f ? v : expm1f(v);
                x1[((size_t)nl * 1764 + p) * 32 + nt * 16 + c16] = f2bf(v);
            }
        }
    }
}

// ============================================================================
// convN (conv2/3/4): channel-last bf16 in, 3x3 s2 p1, Cin=Cout=32, K=288.
// ============================================================================
template<int HI, int HO, int OUTMODE>
__global__ __launch_bounds__(256) void convN_kernel(
    const bf16* __restrict__ xin, bf16* __restrict__ xout,
    const bf16* __restrict__ wBg, const float* __restrict__ bias, int n0)
{
    constexpr int NPIX = HO * HO;
    constexpr int NBLK = (NPIX + 63) / 64;
    __shared__ bf16 A[64 * 296];       // 37,888 B
    __shared__ bf16 wBs[9216];         // 18,432 B
    int tid = threadIdx.x;
    int nl = blockIdx.x / NBLK, blk = blockIdx.x % NBLK;
    int p0 = blk * 64;
    for (int i = tid; i < 1152; i += 256) ((uint4*)wBs)[i] = ((const uint4*)wBg)[i];
    const bf16* xb = xin + (size_t)nl * HI * HI * 32;
    for (int i = tid; i < 2304; i += 256) {
        int m = i / 36, t = i % 36, kk = t >> 2, part = t & 3;
        int kh = kk / 3, kw = kk - kh * 3;
        int p = p0 + m;
        uint4 v; v.x = v.y = v.z = v.w = 0u;
        if (p < NPIX) {
            int oy = p / HO, ox = p - oy * HO;
            int y = 2 * oy - 1 + kh, x = 2 * ox - 1 + kw;
            if ((unsigned)y < (unsigned)HI && (unsigned)x < (unsigned)HI)
                v = *(const uint4*)&xb[((size_t)(y * HI + x)) * 32 + part * 8];
        }
        *(uint4*)&A[m * 296 + kk * 32 + part * 8] = v;
    }
    __syncthreads();
    int lane = tid & 63, g = tid >> 6, quad = lane >> 4, c16 = lane & 15;
    int ma = g * 16 + c16;
    short8 af[9];
    #pragma unroll
    for (int kk = 0; kk < 9; kk++)
        af[kk] = *(const short8*)&A[ma * 296 + kk * 32 + quad * 8];
    #pragma unroll
    for (int nt = 0; nt < 2; nt++) {
        float bv = bias[nt * 16 + c16];
        f32x4 acc = {bv, bv, bv, bv};
        #pragma unroll
        for (int kk = 0; kk < 9; kk++) {
            short8 bfr = *(const short8*)&wBs[((nt * 9 + kk) * 64 + lane) * 8];
            acc = MFMA(af[kk], bfr, acc);
        }
        #pragma unroll
        for (int r = 0; r < 4; r++) {
            int p = p0 + g * 16 + 4 * quad + r;
            if (p < NPIX) {
                float v = acc[r];
                v = v > 0.0f ? v : expm1f(v);
                if (OUTMODE == 0)
                    xout[(((size_t)(n0 + nl)) * NPIX + p) * 32 + nt * 16 + c16] = f2bf(v);
                else
                    xout[(size_t)(n0 + nl) * FEAT + (nt * 16 + c16) * 36 + p] = f2bf(v);
            }
        }
    }
}

// ============================================================================
// GI = x4 @ W_ih^T + biasg : [2048,1152]bf16 x [1152,768] -> f32. MFMA.
// ============================================================================
__global__ __launch_bounds__(256) void gemm_gi_kernel(
    const bf16* __restrict__ X, const bf16* __restrict__ wihF,
    const float* __restrict__ biasg, float* __restrict__ GI)
{
    __shared__ bf16 As[64 * 40];
    int tid = threadIdx.x;
    int m0 = blockIdx.x * 64, nb = blockIdx.y * 4, n0 = blockIdx.y * 64;
    int lane = tid & 63, g = tid >> 6, quad = lane >> 4, c16 = lane & 15;
    f32x4 acc[4];
    #pragma unroll
    for (int st = 0; st < 4; st++) {
        float bv = biasg[n0 + st * 16 + c16];
        acc[st] = (f32x4){bv, bv, bv, bv};
    }
    int sm = tid >> 2, sp = tid & 3;
    for (int ch = 0; ch < 36; ch++) {
        __syncthreads();
        *(uint4*)&As[sm * 40 + sp * 8] =
            *(const uint4*)&X[(size_t)(m0 + sm) * FEAT + ch * 32 + sp * 8];
        __syncthreads();
        short8 af = *(const short8*)&As[(g * 16 + c16) * 40 + quad * 8];
        #pragma unroll
        for (int st = 0; st < 4; st++) {
            short8 bfr = *(const short8*)&wihF[(((size_t)ch * 48 + nb + st) * 64 + lane) * 8];
            acc[st] = MFMA(af, bfr, acc[st]);
        }
    }
    #pragma unroll
    for (int st = 0; st < 4; st++)
        #pragma unroll
        for (int r = 0; r < 4; r++)
            GI[(size_t)(m0 + g * 16 + 4 * quad + r) * G3 + n0 + st * 16 + c16] = acc[st][r];
}

// ============================================================================
// GRU scan: 32 blocks x 768 threads (one per gate-column).
//
// Round-3 fix: rocprof showed VGPR_Count=84 in BOTH prior rounds — 84 =
// 512/6 (granule-rounded), i.e. the compiler allocated for 6 waves/SIMD =
// 2 resident 12-wave blocks per CU. __launch_bounds__(768, 3)'s second arg
// acts as a CUDA-style min-BLOCKS/occupancy target here, so the VGPR cap was
// 84 and the 24 pinned uint4 (96 VGPRs) were force-spilled regardless of
// source-level pinning. Grid is 32 blocks on 256 CUs -> 2-block residency
// buys nothing. (768, 1) -> 3 waves/SIMD -> cap ~168: 96 pinned + ~32 live
// streamed/working fits with slack.
//
// Scheme: 24 uint4 (96 VGPR, k=0..191) pinned via opaque asm; 8 uint4
// (k=192..255) streamed from L2 each step through a per-iteration opaqued
// pointer (blocks LICM), issued at loop top, consumed ~3000 cy later.
// Dot uses 4 independent acc chains.
// ============================================================================
#define UNPK_LO(u) __uint_as_float((u) << 16)
#define UNPK_HI(u) __uint_as_float((u) & 0xffff0000u)
#define WDOT8(Wv, hbase, A_) {                                                 \
    float4 h0 = *(const float4*)&hs[(hbase)];                                  \
    float4 h1 = *(const float4*)&hs[(hbase) + 4];                              \
    A_ = fmaf(h0.x, UNPK_LO((Wv).x), A_);                                      \
    A_ = fmaf(h0.y, UNPK_HI((Wv).x), A_);                                      \
    A_ = fmaf(h0.z, UNPK_LO((Wv).y), A_);                                      \
    A_ = fmaf(h0.w, UNPK_HI((Wv).y), A_);                                      \
    A_ = fmaf(h1.x, UNPK_LO((Wv).z), A_);                                      \
    A_ = fmaf(h1.y, UNPK_HI((Wv).z), A_);                                      \
    A_ = fmaf(h1.z, UNPK_LO((Wv).w), A_);                                      \
    A_ = fmaf(h1.w, UNPK_HI((Wv).w), A_); }

__global__ __launch_bounds__(768, 1) void scan_kernel(
    const float* __restrict__ GI, const bf16* __restrict__ whh16,
    const float* __restrict__ b_hh, const float* __restrict__ rnn_in,
    const float* __restrict__ mask, float* __restrict__ H)
{
    __shared__ float hs[HID];
    __shared__ float pr[HID];
    __shared__ float pz[HID];
    __shared__ float pn[HID];
    int b = blockIdx.x, t = threadIdx.x;
    int gate = t >> 8, j = t & 255;

    const u32x4* wr = (const u32x4*)(whh16 + (size_t)t * HID);
    // k = 0..191 : pinned in VGPRs (96 regs).
    u32x4 w0  = wr[0],  w1  = wr[1],  w2  = wr[2],  w3  = wr[3];
    u32x4 w4  = wr[4],  w5  = wr[5],  w6  = wr[6],  w7  = wr[7];
    u32x4 w8  = wr[8],  w9  = wr[9],  w10 = wr[10], w11 = wr[11];
    u32x4 w12 = wr[12], w13 = wr[13], w14 = wr[14], w15 = wr[15];
    u32x4 w16 = wr[16], w17 = wr[17], w18 = wr[18], w19 = wr[19];
    u32x4 w20 = wr[20], w21 = wr[21], w22 = wr[22], w23 = wr[23];
    asm volatile("" : "+v"(w0), "+v"(w1), "+v"(w2), "+v"(w3),
                      "+v"(w4), "+v"(w5), "+v"(w6), "+v"(w7));
    asm volatile("" : "+v"(w8), "+v"(w9), "+v"(w10), "+v"(w11),
                      "+v"(w12), "+v"(w13), "+v"(w14), "+v"(w15));
    asm volatile("" : "+v"(w16), "+v"(w17), "+v"(w18), "+v"(w19),
                      "+v"(w20), "+v"(w21), "+v"(w22), "+v"(w23));

    float bhn = (gate == 2) ? b_hh[2 * HID + j] : 0.0f;
    if (t < HID) hs[t] = rnn_in[b * HID + t] * mask[b];
    __syncthreads();

    #pragma unroll 1
    for (int step = 0; step < TT; step++) {
        int row = step * BB + b;
        // combiner-thread prefetches (issued before the dot, consumed after barrier)
        float gr = 0.f, gz = 0.f, gn = 0.f, hold = 0.f, mnext = 1.0f;
        if (gate == 0) {
            const float* gp = GI + (size_t)row * G3 + j;
            gr = gp[0]; gz = gp[256]; gn = gp[512];
            hold = hs[j];
            if (step + 1 < TT) mnext = mask[(step + 1) * BB + b];
        }
        // k = 192..255 : streamed from L2 each step. Opaque the pointer per
        // iteration so LICM can't hoist these into long (spilling) live ranges.
        uintptr_t wpo = (uintptr_t)wr;
        asm volatile("" : "+v"(wpo));
        const u32x4* wt = (const u32x4*)wpo;
        u32x4 t24 = wt[24], t25 = wt[25], t26 = wt[26], t27 = wt[27];
        u32x4 t28 = wt[28], t29 = wt[29], t30 = wt[30], t31 = wt[31];

        float a0 = bhn, a1 = 0.f, a2 = 0.f, a3 = 0.f;
        WDOT8(w0,    0, a0)  WDOT8(w1,    8, a1)  WDOT8(w2,   16, a2)  WDOT8(w3,   24, a3)
        WDOT8(w4,   32, a0)  WDOT8(w5,   40, a1)  WDOT8(w6,   48, a2)  WDOT8(w7,   56, a3)
        WDOT8(w8,   64, a0)  WDOT8(w9,   72, a1)  WDOT8(w10,  80, a2)  WDOT8(w11,  88, a3)
        WDOT8(w12,  96, a0)  WDOT8(w13, 104, a1)  WDOT8(w14, 112, a2)  WDOT8(w15, 120, a3)
        WDOT8(w16, 128, a0)  WDOT8(w17, 136, a1)  WDOT8(w18, 144, a2)  WDOT8(w19, 152, a3)
        WDOT8(w20, 160, a0)  WDOT8(w21, 168, a1)  WDOT8(w22, 176, a2)  WDOT8(w23, 184, a3)
        WDOT8(t24, 192, a0)  WDOT8(t25, 200, a1)  WDOT8(t26, 208, a2)  WDOT8(t27, 216, a3)
        WDOT8(t28, 224, a0)  WDOT8(t29, 232, a1)  WDOT8(t30, 240, a2)  WDOT8(t31, 248, a3)
        float acc = (a0 + a1) + (a2 + a3);

        if (gate == 0)      pr[j] = acc;
        else if (gate == 1) pz[j] = acc;
        else                pn[j] = acc;
        __syncthreads();
        if (gate == 0) {
            float r = 1.0f / (1.0f + expf(-(gr + pr[j])));
            float z = 1.0f / (1.0f + expf(-(gz + pz[j])));
            float pre = gn + r * pn[j];
            pre = fminf(15.0f, fmaxf(-15.0f, pre));
            float e = expf(2.0f * pre);
            float nn = (e - 1.0f) / (e + 1.0f);
            float hnew = (1.0f - z) * nn + z * hold;
            H[(size_t)row * HID + j] = hnew;
            hs[j] = hnew * mnext;
        }
        __syncthreads();
    }
}

// ---------------- heads: v, actions, logp_a, ent (float32 out) ----------------
__global__ __launch_bounds__(256) void heads_kernel(
    const float* __restrict__ H, const int* __restrict__ actions,
    const float* __restrict__ Wc, const float* __restrict__ bc,
    const float* __restrict__ Wa, const float* __restrict__ ba,
    float* __restrict__ out)
{
    int r = blockIdx.x * 256 + threadIdx.x;
    if (r >= NB) return;
    const float* h = H + (size_t)r * HID;
    float v = bc[0];
    for (int k = 0; k < HID; k++) v += h[k] * Wc[k];
    float lg[NA];
    for (int a = 0; a < NA; a++) {
        float s = ba[a];
        const float* wa = Wa + a * HID;
        for (int k = 0; k < HID; k++) s += h[k] * wa[k];
        lg[a] = s;
    }
    float mx = lg[0];
    for (int a = 1; a < NA; a++) mx = fmaxf(mx, lg[a]);
    float Z = 0.f;
    for (int a = 0; a < NA; a++) Z += expf(lg[a] - mx);
    float lse = mx + logf(Z);
    int act = actions[r];
    float logp_a = lg[act] - lse;
    float ent = 0.f;
    for (int a = 0; a < NA; a++) {
        float lp = lg[a] - lse;
        ent -= expf(lp) * lp;
    }
    out[r]          = v;
    out[NB + r]     = (float)act;
    out[2 * NB + r] = logp_a;
    out[3 * NB + r] = ent;
}

__global__ __launch_bounds__(256) void hfin_kernel(const float* __restrict__ H, float* __restrict__ out)
{
    int i = blockIdx.x * 256 + threadIdx.x;
    if (i < BB * HID)
        out[4 * NB + i] = H[(size_t)(TT - 1) * BB * HID + i];
}

extern "C" void kernel_launch(void* const* d_in, const int* in_sizes, int n_in,
                              void* d_out, int out_size, void* d_ws, size_t ws_size,
                              hipStream_t stream) {
    const float* inputs  = (const float*)d_in[0];
    const float* rnn_in  = (const float*)d_in[1];
    const float* mask    = (const float*)d_in[2];
    const int*   actions = (const int*)d_in[3];
    const float* w1 = (const float*)d_in[4];
    const float* b1 = (const float*)d_in[5];
    const float* w2 = (const float*)d_in[6];
    const float* b2 = (const float*)d_in[7];
    const float* w3 = (const float*)d_in[8];
    const float* b3 = (const float*)d_in[9];
    const float* w4 = (const float*)d_in[10];
    const float* b4 = (const float*)d_in[11];
    const float* W_ih = (const float*)d_in[12];
    const float* W_hh = (const float*)d_in[13];
    const float* b_ih = (const float*)d_in[14];
    const float* b_hh = (const float*)d_in[15];
    const float* Wc = (const float*)d_in[16];
    const float* bc = (const float*)d_in[17];
    const float* Wa = (const float*)d_in[18];
    const float* ba = (const float*)d_in[19];
    float* out = (float*)d_out;

    char* ws = (char*)d_ws;
    size_t o = 0;
    auto nxt = [&](size_t b) { void* p = ws + o; o += (b + 255) & ~(size_t)255; return p; };
    bf16* wB1  = (bf16*)nxt(2048 * 2);
    bf16* wB2  = (bf16*)nxt(9216 * 2);
    bf16* wB3  = (bf16*)nxt(9216 * 2);
    bf16* wB4  = (bf16*)nxt(9216 * 2);
    bf16* wihF = (bf16*)nxt(884736 * 2);
    bf16* whh16 = (bf16*)nxt(196608 * 2);
    float* biasg = (float*)nxt(768 * 4);
    bf16* x4 = (bf16*)nxt((size_t)NB * FEAT * 2);            //  4.72 MB
    bf16* x2 = (bf16*)nxt((size_t)NB * 441 * 32 * 2);        // 57.80 MB

    // dynamic conv1/conv2 chunking based on available workspace
    const size_t X1_PER_IMG = 1764 * 32 * 2;                  // 112,896 B
    const size_t TAILFIX = 15859712 + 6291456 + 2097152 + 1024; // x3+GI+H
    bf16* x3; float* GI; float* H; bf16* x1c;
    int CH;
    if (ws_size >= o + TAILFIX + 2048 * X1_PER_IMG + (1u << 20)) {
        CH = 2048;
        x3 = (bf16*)nxt(15859712); GI = (float*)nxt(6291456); H = (float*)nxt(2097152);
        x1c = (bf16*)nxt(2048 * X1_PER_IMG);
    } else if (ws_size >= o + TAILFIX + 512 * X1_PER_IMG + (1u << 20)) {
        CH = 512;
        x3 = (bf16*)nxt(15859712); GI = (float*)nxt(6291456); H = (float*)nxt(2097152);
        x1c = (bf16*)nxt(512 * X1_PER_IMG);
    } else if (ws_size >= o + TAILFIX + 256 * X1_PER_IMG + (1u << 20)) {
        CH = 256;
        x3 = (bf16*)nxt(15859712); GI = (float*)nxt(6291456); H = (float*)nxt(2097152);
        x1c = (bf16*)nxt(256 * X1_PER_IMG);
    } else {
        // known-good overlay layout (93.7 MB total): x1c shares region with x3/GI/H
        CH = 256;
        char* R1 = (char*)nxt(28901376);
        x1c = (bf16*)R1;
        x3  = (bf16*)R1;
        GI  = (float*)(R1 + 15859712);
        H   = (float*)(R1 + 15859712 + 6291456);
    }

    prep_kernel<<<3456, 256, 0, stream>>>(w1, w2, w3, w4, W_ih, W_hh, b_ih, b_hh,
                                          wB1, wB2, wB3, wB4, wihF, whh16, biasg);
    for (int c = 0; c < 2048 / CH; c++) {
        conv1_kernel<<<CH * 28, 256, 0, stream>>>(inputs, c * CH, wB1, b1, x1c);
        convN_kernel<42, 21, 0><<<CH * 7, 256, 0, stream>>>(x1c, x2, wB2, b2, c * CH);
    }
    convN_kernel<21, 11, 0><<<2048 * 2, 256, 0, stream>>>(x2, x3, wB3, b3, 0);
    convN_kernel<11, 6, 1><<<2048, 256, 0, stream>>>(x3, x4, wB4, b4, 0);
    gemm_gi_kernel<<<dim3(32, 12), 256, 0, stream>>>(x4, wihF, biasg, GI);
    scan_kernel<<<BB, 768, 0, stream>>>(GI, whh16, b_hh, rnn_in, mask, H);
    heads_kernel<<<NB / 256, 256, 0, stream>>>(H, actions, Wc, bc, Wa, ba, out);
    hfin_kernel<<<(BB * HID + 255) / 256, 256, 0, stream>>>(H, out);
}